// Round 4
// baseline (2050.815 us; speedup 1.0000x reference)
//
#include <hip/hip_runtime.h>
#include <cstdint>
#include <cstddef>

// SNN_53618371723788: 2-layer SLSTM, B=65536, T=24, H=64, fp32.
//
// R15: FUSED single kernel. Evidence: R14's prefetch was a no-op; per-CU
// accounting shows pass1 at VALU 55%/LDS 58% and pass2 at VALU 43%/LDS 70%
// -- both stall-bound with complementary slack. Fuse L1+L2 per wave:
// spike masks go ballot->SGPR (no global round-trip), mem1 stays in regs,
// one staging, zero t-loop barriers (per-wave stM strip -> waves desync
// and fill each other's stalls). LDS holds Pih+Phh+stM = 160KB exactly;
// Whh1 is served from a prepacked transposed global table (64KB,
// L2-resident, coalesced, dense/prefetchable). Arithmetic order identical
// to the 2-pass version: absmax must stay 0.0.

#define BB 65536
#define TT 24
#define NB 8  // batch elements per wave (two halves of 4)

__device__ __forceinline__ float bcastf(float v, int l) {
  return __int_as_float(__builtin_amdgcn_readlane(__float_as_int(v), l));
}
__device__ __forceinline__ float sigm(float v) {
  return __fdividef(1.0f, 1.0f + __expf(-v));  // v_exp + v_rcp path
}
__device__ __forceinline__ float tanh_fast(float v) {
  // tanh(x) = 1 - 2/(e^{2x}+1); e^inf->inf, rcp(inf)->0 => saturates to +-1
  return fmaf(-2.0f, __fdividef(1.0f, __expf(2.0f * v) + 1.0f), 1.0f);
}
__device__ __forceinline__ float wsum(float v) {
#pragma unroll
  for (int o = 32; o > 0; o >>= 1) v += __shfl_xor(v, o);
  return v;
}

// Prepack Whh1 into the transposed float4 table the main kernel streams:
// p1t[m*64+l] = {Whh1[l][m], Whh1[64+l][m], Whh1[128+l][m], Whh1[192+l][m]}
__global__ __launch_bounds__(1024) void prepack_p1t(
    const float* __restrict__ Whh1, float4* __restrict__ p1t) {
  int i = blockIdx.x * 1024 + threadIdx.x;
  if (i < 4096) {
    int m = i >> 6, l = i & 63;
    p1t[i] = make_float4(Whh1[l * 64 + m], Whh1[(64 + l) * 64 + m],
                         Whh1[(128 + l) * 64 + m], Whh1[(192 + l) * 64 + m]);
  }
}

__global__ __attribute__((amdgpu_waves_per_eu(4, 4))) __launch_bounds__(1024)
void snn_fused(
    const float* __restrict__ x, const float* __restrict__ Wih1,
    const float4* __restrict__ P1T, const float* __restrict__ bih1,
    const float* __restrict__ bhh1, const float* __restrict__ thr1p,
    const float* __restrict__ Wih2, const float* __restrict__ Whh2,
    const float* __restrict__ bih2, const float* __restrict__ bhh2,
    const float* __restrict__ thr2p, const float* __restrict__ Wout,
    const float* __restrict__ bout, float* __restrict__ out) {
  __shared__ float4 Pih[64][64];     // 64 KB (Wih2 transposed)
  __shared__ float4 Phh[64][64];     // 64 KB (Whh2 transposed)
  __shared__ float stM[16][64][NB];  // 32 KB -> 160 KB total (1 block/CU)
  int tid = threadIdx.x;
  int lane = tid & 63, wave = tid >> 6;
  int wb = (blockIdx.x * 16 + wave) * NB;

  // preload this wave's entire x window: lane t holds x[b][t] (t<24)
  float xv[NB];
  int lt = (lane < TT) ? lane : (TT - 1);
#pragma unroll
  for (int b = 0; b < NB; b++) xv[b] = x[(size_t)(wb + b) * TT + lt];

  for (int idx = tid; idx < 16384; idx += 1024) {
    int k = idx >> 6, m = idx & 63;
    ((float*)&Pih[m][k & 63])[k >> 6] = Wih2[idx];
    ((float*)&Phh[m][k & 63])[k >> 6] = Whh2[idx];
  }
  __syncthreads();

  float thr1 = thr1p[0], thr2 = thr2p[0];
  float b1q[4], wq[4], b2q[4];
#pragma unroll
  for (int q = 0; q < 4; q++) {
    b1q[q] = bih1[q * 64 + lane] + bhh1[q * 64 + lane];
    wq[q] = Wih1[q * 64 + lane];
    b2q[q] = bih2[q * 64 + lane] + bhh2[q * 64 + lane];
  }
  float syn1[NB], mem1[NB], syn2[NB], mem2[NB];
  unsigned sb8[NB];  // per-lane spike history of THIS lane's neuron, bit t
#pragma unroll
  for (int b = 0; b < NB; b++) {
    syn1[b] = 0.0f; mem1[b] = 0.0f; syn2[b] = 0.0f; mem2[b] = 0.0f;
    sb8[b] = 0u;
  }
  unsigned long long mk[NB];  // wave-uniform spike masks (SGPRs)

  for (int t = 0; t < TT; t++) {
    // ---------------- layer 1 ----------------
#pragma unroll
    for (int b = 0; b < NB; b++) stM[wave][lane][b] = mem1[b];
#pragma unroll
    for (int h = 0; h < 2; h++) {
      const int B0 = h * 4;
      float acc[4][4];
#pragma unroll
      for (int j = 0; j < 4; j++) {
        float xbt = bcastf(xv[B0 + j], t);  // v_readlane, no global load
#pragma unroll
        for (int q = 0; q < 4; q++) acc[j][q] = fmaf(xbt, wq[q], b1q[q]);
      }
#pragma unroll 8
      for (int m = 0; m < 64; m++) {
        float4 w = P1T[m * 64 + lane];                   // global (L2-hot)
        float4 sa = *(const float4*)&stM[wave][m][B0];   // broadcast read
        float s[4] = {sa.x, sa.y, sa.z, sa.w};
#pragma unroll
        for (int j = 0; j < 4; j++) {
          acc[j][0] = fmaf(s[j], w.x, acc[j][0]);
          acc[j][1] = fmaf(s[j], w.y, acc[j][1]);
          acc[j][2] = fmaf(s[j], w.z, acc[j][2]);
          acc[j][3] = fmaf(s[j], w.w, acc[j][3]);
        }
      }
#pragma unroll
      for (int j = 0; j < 4; j++) {
        int b = B0 + j;
        float ig = sigm(acc[j][0]), fg = sigm(acc[j][1]);
        float gg = tanh_fast(acc[j][2]), og = sigm(acc[j][3]);
        float sn = fmaf(fg, syn1[b], ig * gg);
        float rst = (mem1[b] > thr1) ? thr1 : 0.0f;  // reset uses OLD mem
        float mn = fmaf(og, tanh_fast(sn), -rst);
        syn1[b] = sn;
        mem1[b] = mn;
        mk[b] = __ballot(mn > thr1);  // wave-uniform mask, straight to SGPR
      }
      __builtin_amdgcn_sched_barrier(0);  // keep halves separate (live-set cap)
    }
    // ---------------- layer 2 ----------------
    // overwrite the per-wave strip with mem2 (per-wave in-order LDS: safe)
#pragma unroll
    for (int b = 0; b < NB; b++) stM[wave][lane][b] = mem2[b];
#pragma unroll
    for (int h = 0; h < 2; h++) {
      const int B0 = h * 4;
      float acc[4][4];
#pragma unroll
      for (int j = 0; j < 4; j++) {
#pragma unroll
        for (int q = 0; q < 4; q++) acc[j][q] = b2q[q];
      }
      // dense hh half (mem2 is dense)
#pragma unroll 4
      for (int m = 0; m < 64; m++) {
        float4 wh = Phh[m][lane];
        float4 sa = *(const float4*)&stM[wave][m][B0];  // broadcast read
        float s[4] = {sa.x, sa.y, sa.z, sa.w};
#pragma unroll
        for (int j = 0; j < 4; j++) {
          acc[j][0] = fmaf(s[j], wh.x, acc[j][0]);
          acc[j][1] = fmaf(s[j], wh.y, acc[j][1]);
          acc[j][2] = fmaf(s[j], wh.z, acc[j][2]);
          acc[j][3] = fmaf(s[j], wh.w, acc[j][3]);
        }
      }
      // sparse ih half: 4-deep read pipeline, adds in ascending bit order.
#pragma unroll
      for (int j = 0; j < 4; j++) {
        int b = B0 + j;
        unsigned long long k = mk[b];
        while (__builtin_popcountll(k) >= 4) {
          int m0 = __builtin_ctzll(k); k &= k - 1;
          int m1 = __builtin_ctzll(k); k &= k - 1;
          int m2 = __builtin_ctzll(k); k &= k - 1;
          int m3 = __builtin_ctzll(k); k &= k - 1;
          float4 r0 = Pih[m0][lane];
          float4 r1 = Pih[m1][lane];
          float4 r2 = Pih[m2][lane];
          float4 r3 = Pih[m3][lane];  // 4 reads in flight before first consume
          acc[j][0] += r0.x; acc[j][1] += r0.y; acc[j][2] += r0.z; acc[j][3] += r0.w;
          acc[j][0] += r1.x; acc[j][1] += r1.y; acc[j][2] += r1.z; acc[j][3] += r1.w;
          acc[j][0] += r2.x; acc[j][1] += r2.y; acc[j][2] += r2.z; acc[j][3] += r2.w;
          acc[j][0] += r3.x; acc[j][1] += r3.y; acc[j][2] += r3.z; acc[j][3] += r3.w;
        }
        while (k) {
          int m0 = __builtin_ctzll(k); k &= k - 1;
          float4 r0 = Pih[m0][lane];
          acc[j][0] += r0.x; acc[j][1] += r0.y; acc[j][2] += r0.z; acc[j][3] += r0.w;
        }
        float ig = sigm(acc[j][0]), fg = sigm(acc[j][1]);
        float gg = tanh_fast(acc[j][2]), og = sigm(acc[j][3]);
        float sn = fmaf(fg, syn2[b], ig * gg);
        float rst = (mem2[b] > thr2) ? thr2 : 0.0f;
        float mn = fmaf(og, tanh_fast(sn), -rst);
        syn2[b] = sn;
        mem2[b] = mn;
        sb8[b] |= (mn > thr2) ? (1u << t) : 0u;
      }
      __builtin_amdgcn_sched_barrier(0);  // keep halves separate (live-set cap)
    }
  }

  // extra step: input = final mem1 (registers now, bit-exact vs fp32 store).
  float acc[NB][4];
#pragma unroll
  for (int b = 0; b < NB; b++) {
#pragma unroll
    for (int q = 0; q < 4; q++) acc[b][q] = b2q[q];
  }
#pragma unroll 4
  for (int m = 0; m < 64; m++) {
    float4 wi = Pih[m][lane];
    float4 wh = Phh[m][lane];
#pragma unroll
    for (int b = 0; b < NB; b++) {
      float s1 = bcastf(mem1[b], m);
      float s2 = bcastf(mem2[b], m);
      acc[b][0] = fmaf(s1, wi.x, fmaf(s2, wh.x, acc[b][0]));
      acc[b][1] = fmaf(s1, wi.y, fmaf(s2, wh.y, acc[b][1]));
      acc[b][2] = fmaf(s1, wi.z, fmaf(s2, wh.z, acc[b][2]));
      acc[b][3] = fmaf(s1, wi.w, fmaf(s2, wh.w, acc[b][3]));
    }
  }
  // epilogue: replay p0/p1 accumulation (same fmaf order as before) from bits.
  float p0[NB], p1[NB];
#pragma unroll
  for (int b = 0; b < NB; b++) { p0[b] = 0.0f; p1[b] = 0.0f; }
#pragma unroll 4
  for (int t = 0; t < TT; t++) {
    float w0 = Wout[t * 64 + lane];
    float w1 = Wout[1664 + t * 64 + lane];
#pragma unroll
    for (int b = 0; b < NB; b++) {
      float sf = ((sb8[b] >> t) & 1u) ? 1.0f : 0.0f;
      p0[b] = fmaf(sf, w0, p0[b]);
      p1[b] = fmaf(sf, w1, p1[b]);
    }
  }
  float wA0 = Wout[1536 + lane], wA1 = Wout[1664 + 1536 + lane];  // spk2_last
  float wB0 = Wout[1600 + lane], wB1 = Wout[1664 + 1600 + lane];  // mem2 final
  float bo0 = bout[0], bo1 = bout[1];
#pragma unroll
  for (int b = 0; b < NB; b++) {
    float ig = sigm(acc[b][0]), fg = sigm(acc[b][1]);
    float gg = tanh_fast(acc[b][2]), og = sigm(acc[b][3]);
    float sn = fmaf(fg, syn2[b], ig * gg);
    float rst = (mem2[b] > thr2) ? thr2 : 0.0f;
    float mn = fmaf(og, tanh_fast(sn), -rst);
    float sf = (mn > thr2) ? 1.0f : 0.0f;
    p0[b] = fmaf(sf, wA0, p0[b]);
    p1[b] = fmaf(sf, wA1, p1[b]);
    p0[b] = fmaf(mn, wB0, p0[b]);
    p1[b] = fmaf(mn, wB1, p1[b]);
  }
  // cross-lane reduce; wsum result is uniform, keep own lane's value.
  float vout = 0.0f;
#pragma unroll
  for (int b = 0; b < NB; b++) {
    float r0 = wsum(p0[b]);
    float r1 = wsum(p1[b]);
    if (lane == 2 * b) vout = r0;
    if (lane == 2 * b + 1) vout = r1;
  }
  if (lane < 2 * NB)
    out[(size_t)wb * 2 + lane] = vout + ((lane & 1) ? bo1 : bo0);
}

extern "C" void kernel_launch(void* const* d_in, const int* in_sizes, int n_in,
                              void* d_out, int out_size, void* d_ws, size_t ws_size,
                              hipStream_t stream) {
  const float* x = (const float*)d_in[0];
  const float* Wih1 = (const float*)d_in[1];
  const float* Whh1 = (const float*)d_in[2];
  const float* bih1 = (const float*)d_in[3];
  const float* bhh1 = (const float*)d_in[4];
  const float* thr1 = (const float*)d_in[5];
  const float* Wih2 = (const float*)d_in[6];
  const float* Whh2 = (const float*)d_in[7];
  const float* bih2 = (const float*)d_in[8];
  const float* bhh2 = (const float*)d_in[9];
  const float* thr2 = (const float*)d_in[10];
  const float* Wout = (const float*)d_in[11];
  const float* bout = (const float*)d_in[12];

  float4* p1t = (float4*)d_ws;  // 64 KB transposed Whh1 table

  prepack_p1t<<<4, 1024, 0, stream>>>(Whh1, p1t);
  snn_fused<<<BB / (16 * NB), 1024, 0, stream>>>(
      x, Wih1, p1t, bih1, bhh1, thr1, Wih2, Whh2, bih2, bhh2, thr2, Wout, bout,
      (float*)d_out);
}